// Round 1
// 118.828 us; speedup vs baseline: 1.0371x; 1.0371x over previous
//
#include <hip/hip_runtime.h>
#include <math.h>

#define N_NODES 10000
#define N_EDGES 160000
#define CAP 64

// D1 task split: scores | bucket (4 edges/thread) | W'' precompute
#define NB_SCORE 40
#define NB_BUCKET 157           // 157*256*4 = 160768 >= N_EDGES (guarded)
#define NB_WPP 9
#define NB_D1 (NB_SCORE + NB_BUCKET + NB_WPP)

typedef short bf16x8 __attribute__((ext_vector_type(8)));
typedef float f32x4 __attribute__((ext_vector_type(4)));

// Self-resetting bucket counters: zero-initialized at module load; k_node
// resets each entry after consuming it, so every launch (correctness call,
// graph replays) starts from all-zero without a memset dispatch.
__device__ int g_cur[N_NODES];

// ---------- helpers ----------
__device__ __forceinline__ unsigned short f2bf(float f) {
    unsigned int x = __float_as_uint(f);
    unsigned int r = (x + 0x7fffu + ((x >> 16) & 1u)) >> 16;   // RNE
    return (unsigned short)r;
}
__device__ __forceinline__ float softplus_f(float x) {
    return fmaxf(x, 0.f) + log1pf(__expf(-fabsf(x)));
}

// ---------- D1: scores | bucket | W'' precompute ----------
// W''_k = Wk @ Wout * 0.25 (k=0..3: Wr[h]; k=4..7: Wt[h]; k=8: -sum of all 8),
// stored TRANSPOSED: wppT[c*576 + k*64 + f] (bf16), c = out column.
__global__ void __launch_bounds__(256) k_prep(const float* __restrict__ x,
                                              const float* __restrict__ wproj,
                                              const float* __restrict__ wrad,
                                              const float* __restrict__ wtan,
                                              const float* __restrict__ rsc,
                                              const float* __restrict__ tsc,
                                              const float* __restrict__ wout,
                                              const int* __restrict__ ei,
                                              const float* __restrict__ el,
                                              float* __restrict__ rts,
                                              int2* __restrict__ sbuf,
                                              unsigned short* __restrict__ wppT) {
    __shared__ __align__(16) float smem[8192];   // 32 KB
    int b = blockIdx.x;
    int t = threadIdx.x;

    if (b < NB_SCORE) {
        // ---- per-node logit scalars rts[n][0..3]=r, [4..7]=t (f32 exact path) ----
        float* vrl = smem;            // 256 floats
        float* vtl = smem + 256;
        {
            // float4 loads: 16 iters instead of 64 scalar 256B-strided loads
            int h = t >> 6, f = t & 63;
            const float4* wv = (const float4*)(wproj + h * 4096 + f * 64);
            const float4* rv = (const float4*)(rsc + h * 64);
            const float4* tv = (const float4*)(tsc + h * 64);
            float ar = 0.f, at = 0.f;
#pragma unroll
            for (int g = 0; g < 16; ++g) {
                float4 w = wv[g];
                float4 r = rv[g];
                float4 s2 = tv[g];
                ar += w.x * r.x + w.y * r.y + w.z * r.z + w.w * r.w;
                at += w.x * s2.x + w.y * s2.y + w.z * s2.z + w.w * s2.w;
            }
            vrl[t] = ar;
            vtl[t] = at;
        }
        __syncthreads();
        int n = b * 256 + t;
        if (n >= N_NODES) return;
        const float4* xr = (const float4*)(x + n * 64);
        float accr[4] = {0.f, 0.f, 0.f, 0.f};
        float acct[4] = {0.f, 0.f, 0.f, 0.f};
        for (int i = 0; i < 16; ++i) {
            float4 xv = xr[i];
#pragma unroll
            for (int h = 0; h < 4; ++h) {
                float4 a = ((const float4*)vrl)[h * 16 + i];
                accr[h] += xv.x * a.x + xv.y * a.y + xv.z * a.z + xv.w * a.w;
                float4 bb = ((const float4*)vtl)[h * 16 + i];
                acct[h] += xv.x * bb.x + xv.y * bb.y + xv.z * bb.z + xv.w * bb.w;
            }
        }
        ((float4*)rts)[n * 2]     = make_float4(accr[0], accr[1], accr[2], accr[3]);
        ((float4*)rts)[n * 2 + 1] = make_float4(acct[0], acct[1], acct[2], acct[3]);
    } else if (b < NB_SCORE + NB_BUCKET) {
        // ---- bucket edges by receiver, 4 edges/thread via int4/float4 ----
        // (g_cur starts all-zero by invariant; N_EDGES % 4 == 0 so a valid
        //  group is fully valid -> no partial-tail OOB)
        int q = (b - NB_SCORE) * 256 + t;          // group index (4 edges)
        if (q * 4 >= N_EDGES) return;
        int4   sv = ((const int4*)ei)[q];
        int4   rv = ((const int4*)(ei + N_EDGES))[q];
        float4 lv = ((const float4*)el)[q];
        int p0 = atomicAdd(&g_cur[rv.x], 1);
        if (p0 < CAP) sbuf[rv.x * CAP + p0] = make_int2(sv.x, __float_as_int(lv.x));
        int p1 = atomicAdd(&g_cur[rv.y], 1);
        if (p1 < CAP) sbuf[rv.y * CAP + p1] = make_int2(sv.y, __float_as_int(lv.y));
        int p2 = atomicAdd(&g_cur[rv.z], 1);
        if (p2 < CAP) sbuf[rv.z * CAP + p2] = make_int2(sv.z, __float_as_int(lv.z));
        int p3 = atomicAdd(&g_cur[rv.w], 1);
        if (p3 < CAP) sbuf[rv.w * CAP + p3] = make_int2(sv.w, __float_as_int(lv.w));
    } else {
        // ---- W'' precompute, one 64x64x64 f32 GEMM per task ----
        int k = b - NB_SCORE - NB_BUCKET;     // 0..8
        float* wo = smem;                     // wout [g][c]
        float* am = smem + 4096;              // A    [f][g]
        for (int i = 0; i < 16; ++i) wo[t + 256 * i] = wout[t + 256 * i];
        if (k < 8) {
            const float* M = (k < 4) ? (wrad + k * 4096) : (wtan + (k - 4) * 4096);
            for (int i = 0; i < 16; ++i) am[t + 256 * i] = M[t + 256 * i];
        } else {
            for (int i = 0; i < 16; ++i) {
                int e = t + 256 * i;
                float s = 0.f;
#pragma unroll
                for (int h = 0; h < 4; ++h) s += wrad[h * 4096 + e] + wtan[h * 4096 + e];
                am[e] = -s;
            }
        }
        __syncthreads();
        int c = t & 63;
        int fg = t >> 6;                      // 0..3
        for (int j = 0; j < 16; ++j) {
            int f = fg * 16 + j;
            // 4 partial accumulators: break the 64-FMA serial dep chain
            float a0 = 0.f, a1 = 0.f, a2 = 0.f, a3 = 0.f;
#pragma unroll
            for (int g = 0; g < 64; g += 4) {
                a0 += am[f * 64 + g]     * wo[g * 64 + c];
                a1 += am[f * 64 + g + 1] * wo[(g + 1) * 64 + c];
                a2 += am[f * 64 + g + 2] * wo[(g + 2) * 64 + c];
                a3 += am[f * 64 + g + 3] * wo[(g + 3) * 64 + c];
            }
            wppT[c * 576 + k * 64 + f] = f2bf(((a0 + a1) + (a2 + a3)) * 0.25f);
        }
    }
}

// ---------- D2: softmax + alpha-weighted x-sums + fused output GEMM (MFMA) ----------
// Block = 512 threads = 8 waves = 8 nodes (1 node/wave), grid 1250.
// 4 blocks/CU (wave-capped) -> finer scheduling quantum, ~20% less tail than
// the 625x1024 shape. Stage B: 16x16 MFMA with A rows 8..15 unused (MFMA D
// rows depend only on matching A rows; stores guarded to rows < 8).
__global__ void __launch_bounds__(512, 8) k_node(const int2* __restrict__ sbuf,
                                                 const float* __restrict__ rts,
                                                 const float* __restrict__ rdls,
                                                 const float* __restrict__ tb,
                                                 const float* __restrict__ tw,
                                                 const float* __restrict__ x,
                                                 const unsigned short* __restrict__ wppT,
                                                 float* __restrict__ out) {
    __shared__ __align__(16) unsigned short accL[16 * 584];   // 18688 B (rows 8..15 unused)
    __shared__ __align__(16) float aldsb[8][CAP * 8];         // 16384 B
    __shared__ int sldsb[8][CAP];                             // 2048 B
    int t = threadIdx.x;
    int wid = t >> 6, lane = t & 63;
    int blk = blockIdx.x;

    float scale = softplus_f(rdls[0]);
    float tb0 = tb[0], tb1 = tb[1], tb2 = tb[2], tb3 = tb[3];
    float tw0 = tw[0], tw1 = tw[1], tw2 = tw[2], tw3 = tw[3];
    float* alds = aldsb[wid];
    int*   slds = sldsb[wid];

    int n = blk * 8 + wid;                    // 1250*8 == N_NODES exactly
    int deg = min(g_cur[n], CAP);
    if (lane == 0) g_cur[n] = 0;              // reset for next launch

    float4 rsr = ((const float4*)rts)[n * 2];
    float4 tsr = ((const float4*)rts)[n * 2 + 1];

    const float NEG = -3.402823466e38f;
    float rl0 = NEG, rl1 = NEG, rl2 = NEG, rl3 = NEG;
    float tl0 = NEG, tl1 = NEG, tl2 = NEG, tl3 = NEG;
    int s_e = 0;
    if (lane < deg) {
        int2 sl = sbuf[n * CAP + lane];
        s_e = sl.x;
        float len = __int_as_float(sl.y);
        float4 rss = ((const float4*)rts)[s_e * 2];
        float4 tss = ((const float4*)rts)[s_e * 2 + 1];
        float sl0 = scale * len;
        // rcp instead of 4 full-precision divides (~1 ULP, well under tolerance)
        float i0 = __builtin_amdgcn_rcpf(softplus_f(tb0 + tw0 * len) + 1e-4f);
        float i1 = __builtin_amdgcn_rcpf(softplus_f(tb1 + tw1 * len) + 1e-4f);
        float i2 = __builtin_amdgcn_rcpf(softplus_f(tb2 + tw2 * len) + 1e-4f);
        float i3 = __builtin_amdgcn_rcpf(softplus_f(tb3 + tw3 * len) + 1e-4f);
        rl0 = ((rss.x - rsr.x) - sl0) * i0;
        rl1 = ((rss.y - rsr.y) - sl0) * i1;
        rl2 = ((rss.z - rsr.z) - sl0) * i2;
        rl3 = ((rss.w - rsr.w) - sl0) * i3;
        tl0 = tss.x - tsr.x;
        tl1 = tss.y - tsr.y;
        tl2 = tss.z - tsr.z;
        tl3 = tss.w - tsr.w;
    }
    float mr0 = rl0, mr1 = rl1, mr2 = rl2, mr3 = rl3;
    float mt0 = tl0, mt1 = tl1, mt2 = tl2, mt3 = tl3;
#pragma unroll
    for (int d = 32; d >= 1; d >>= 1) {
        mr0 = fmaxf(mr0, __shfl_xor(mr0, d)); mr1 = fmaxf(mr1, __shfl_xor(mr1, d));
        mr2 = fmaxf(mr2, __shfl_xor(mr2, d)); mr3 = fmaxf(mr3, __shfl_xor(mr3, d));
        mt0 = fmaxf(mt0, __shfl_xor(mt0, d)); mt1 = fmaxf(mt1, __shfl_xor(mt1, d));
        mt2 = fmaxf(mt2, __shfl_xor(mt2, d)); mt3 = fmaxf(mt3, __shfl_xor(mt3, d));
    }
    float er0 = 0.f, er1 = 0.f, er2 = 0.f, er3 = 0.f;
    float et0 = 0.f, et1 = 0.f, et2 = 0.f, et3 = 0.f;
    if (lane < deg) {
        er0 = __expf(rl0 - mr0); er1 = __expf(rl1 - mr1);
        er2 = __expf(rl2 - mr2); er3 = __expf(rl3 - mr3);
        et0 = __expf(tl0 - mt0); et1 = __expf(tl1 - mt1);
        et2 = __expf(tl2 - mt2); et3 = __expf(tl3 - mt3);
    }
    float sr0 = er0, sr1 = er1, sr2 = er2, sr3 = er3;
    float st0 = et0, st1 = et1, st2 = et2, st3 = et3;
#pragma unroll
    for (int d = 32; d >= 1; d >>= 1) {
        sr0 += __shfl_xor(sr0, d); sr1 += __shfl_xor(sr1, d);
        sr2 += __shfl_xor(sr2, d); sr3 += __shfl_xor(sr3, d);
        st0 += __shfl_xor(st0, d); st1 += __shfl_xor(st1, d);
        st2 += __shfl_xor(st2, d); st3 += __shfl_xor(st3, d);
    }
    if (lane < deg) {
        // rcp + mul instead of 8 divides
        float isr0 = __builtin_amdgcn_rcpf(sr0), isr1 = __builtin_amdgcn_rcpf(sr1);
        float isr2 = __builtin_amdgcn_rcpf(sr2), isr3 = __builtin_amdgcn_rcpf(sr3);
        float ist0 = __builtin_amdgcn_rcpf(st0), ist1 = __builtin_amdgcn_rcpf(st1);
        float ist2 = __builtin_amdgcn_rcpf(st2), ist3 = __builtin_amdgcn_rcpf(st3);
        float* ap = alds + lane * 8;
        ((float4*)ap)[0] = make_float4(er0 * isr0, er1 * isr1, er2 * isr2, er3 * isr3);
        ((float4*)ap)[1] = make_float4(et0 * ist0, et1 * ist1, et2 * ist2, et3 * ist3);
        slds[lane] = s_e;
    }

    // ---- accumulate V row: lane = feature f; 9 accumulators; 4-way unrolled ----
    float a0 = 0.f, a1 = 0.f, a2 = 0.f, a3 = 0.f;
    float b0 = 0.f, b1 = 0.f, b2 = 0.f, b3 = 0.f;
    int i = 0;
    for (; i + 4 <= deg; i += 4) {
        int s0 = slds[i], s1 = slds[i + 1], s2 = slds[i + 2], s3 = slds[i + 3];
        float xv0 = x[s0 * 64 + lane];
        float xv1 = x[s1 * 64 + lane];
        float xv2 = x[s2 * 64 + lane];
        float xv3 = x[s3 * 64 + lane];
        float4 ar0 = ((const float4*)(alds + i * 8))[0];
        float4 at0 = ((const float4*)(alds + i * 8))[1];
        float4 ar1 = ((const float4*)(alds + (i + 1) * 8))[0];
        float4 at1 = ((const float4*)(alds + (i + 1) * 8))[1];
        float4 ar2 = ((const float4*)(alds + (i + 2) * 8))[0];
        float4 at2 = ((const float4*)(alds + (i + 2) * 8))[1];
        float4 ar3 = ((const float4*)(alds + (i + 3) * 8))[0];
        float4 at3 = ((const float4*)(alds + (i + 3) * 8))[1];
        a0 += ar0.x * xv0 + ar1.x * xv1 + ar2.x * xv2 + ar3.x * xv3;
        a1 += ar0.y * xv0 + ar1.y * xv1 + ar2.y * xv2 + ar3.y * xv3;
        a2 += ar0.z * xv0 + ar1.z * xv1 + ar2.z * xv2 + ar3.z * xv3;
        a3 += ar0.w * xv0 + ar1.w * xv1 + ar2.w * xv2 + ar3.w * xv3;
        b0 += at0.x * xv0 + at1.x * xv1 + at2.x * xv2 + at3.x * xv3;
        b1 += at0.y * xv0 + at1.y * xv1 + at2.y * xv2 + at3.y * xv3;
        b2 += at0.z * xv0 + at1.z * xv1 + at2.z * xv2 + at3.z * xv3;
        b3 += at0.w * xv0 + at1.w * xv1 + at2.w * xv2 + at3.w * xv3;
    }
    for (; i < deg; ++i) {
        int s0 = slds[i];
        float xv0 = x[s0 * 64 + lane];
        float4 ar0 = ((const float4*)(alds + i * 8))[0];
        float4 at0 = ((const float4*)(alds + i * 8))[1];
        a0 += ar0.x * xv0; a1 += ar0.y * xv0; a2 += ar0.z * xv0; a3 += ar0.w * xv0;
        b0 += at0.x * xv0; b1 += at0.y * xv0; b2 += at0.z * xv0; b3 += at0.w * xv0;
    }
    float c8 = (deg > 0) ? x[n * 64 + lane] : 0.f;   // receiver slot (sign in W''_8)

    unsigned short* arow = accL + wid * 584;
    arow[0 * 64 + lane] = f2bf(a0);
    arow[1 * 64 + lane] = f2bf(a1);
    arow[2 * 64 + lane] = f2bf(a2);
    arow[3 * 64 + lane] = f2bf(a3);
    arow[4 * 64 + lane] = f2bf(b0);
    arow[5 * 64 + lane] = f2bf(b1);
    arow[6 * 64 + lane] = f2bf(b2);
    arow[7 * 64 + lane] = f2bf(b3);
    arow[8 * 64 + lane] = f2bf(c8);
    __syncthreads();

    // ---- stage B: [8 x 576] @ W''T -> out[8 x 64]; waves 0..3 ----
    if (wid < 4) {
        int c = lane & 15, q = lane >> 4;
        f32x4 dacc = {0.f, 0.f, 0.f, 0.f};
        const unsigned short* bp = wppT + (16 * wid + c) * 576 + q * 8;
        const unsigned short* ap = accL + c * 584 + q * 8;   // A: m = lane&15 (node row)
#pragma unroll
        for (int kc = 0; kc < 18; ++kc) {
            bf16x8 af = *(const bf16x8*)(ap + kc * 32);
            bf16x8 bf = *(const bf16x8*)(bp + kc * 32);
            dacc = __builtin_amdgcn_mfma_f32_16x16x32_bf16(af, bf, dacc, 0, 0, 0);
        }
#pragma unroll
        for (int r = 0; r < 4; ++r) {
            int row = q * 4 + r;              // D row; rows 8..15 are garbage (unused A rows)
            if (row < 8) {
                int node = blk * 8 + row;
                int col = 16 * wid + c;
                out[node * 64 + col] = x[node * 64 + col] + dacc[r];
            }
        }
    }
}

extern "C" void kernel_launch(void* const* d_in, const int* in_sizes, int n_in,
                              void* d_out, int out_size, void* d_ws, size_t ws_size,
                              hipStream_t stream) {
    const float* x     = (const float*)d_in[0];
    const int*   ei    = (const int*)d_in[1];
    /* d_in[2] edge_vec unused by reference */
    const float* el    = (const float*)d_in[3];
    const float* wproj = (const float*)d_in[4];
    const float* wrad  = (const float*)d_in[5];
    const float* wtan  = (const float*)d_in[6];
    const float* rsc   = (const float*)d_in[7];
    const float* tsc   = (const float*)d_in[8];
    const float* rdls  = (const float*)d_in[9];
    const float* tb    = (const float*)d_in[10];
    const float* tw    = (const float*)d_in[11];
    const float* wout  = (const float*)d_in[12];
    float* out = (float*)d_out;

    char* w = (char*)d_ws;
    size_t o = 0;
    auto nxt = [&](size_t bytes) -> char* {
        char* p = w + o;
        o += (bytes + 255) & ~(size_t)255;
        return p;
    };
    float* rts = (float*)nxt((size_t)N_NODES * 8 * 4);
    int2*  sbuf = (int2*)nxt((size_t)N_NODES * CAP * 8);
    unsigned short* wppT = (unsigned short*)nxt((size_t)64 * 576 * 2);

    k_prep<<<NB_D1, 256, 0, stream>>>(x, wproj, wrad, wtan, rsc, tsc, wout,
                                      ei, el, rts, sbuf, wppT);
    k_node<<<1250, 512, 0, stream>>>(sbuf, rts, rdls, tb, tw, x, wppT, out);
}